// Round 1
// 239.111 us; speedup vs baseline: 1.0596x; 1.0596x over previous
//
#include <hip/hip_runtime.h>
#include <cmath>

#define NH 16
#define NKV 4
#define HD 128
#define DMODEL 2048
#define BB 4
#define SQV 1024
#define SQA 64
#define SCACHE 256
#define STOT 1344   // SCACHE + SQV + SQA
#define SQTOT 1088  // SQV + SQA
#define NSPLIT 7    // attention K-partitions (192 keys = 3 chunks each)

typedef unsigned short u16;
typedef __attribute__((ext_vector_type(8))) short short8;
typedef __attribute__((ext_vector_type(4))) float f32x4;

__device__ __forceinline__ float b2f(u16 u) {
    union { float f; unsigned int i; } x; x.i = ((unsigned int)u) << 16; return x.f;
}
__device__ __forceinline__ u16 f2b(float f) {
    unsigned int x = __float_as_uint(f);
    x = x + 0x7fffu + ((x >> 16) & 1u);   // RNE
    return (u16)(x >> 16);
}

// async global->LDS, 16B per lane. LDS dest is wave-uniform base + lane*16 (linear).
__device__ __forceinline__ void gload16(const void* g, void* l) {
    __builtin_amdgcn_global_load_lds((const __attribute__((address_space(1))) void*)g,
                                     (__attribute__((address_space(3))) void*)l, 16, 0, 0);
}

// ---------------- transpose body: fp32 [2048][N] tile -> bf16 [N][2048] ---------------
__device__ __forceinline__ void transpose_body(const float* in, u16* out, int N,
                                               int bx, int by) {
    __shared__ __align__(16) u16 t[64 * 66];
    int n0 = bx * 64, k0 = by * 64;
    int tid = threadIdx.x;
    int r = tid >> 3;
    int c8 = (tid & 7) * 8;
#pragma unroll
    for (int h = 0; h < 2; h++) {
        int k = r + h * 32;
        const float* f = in + (size_t)(k0 + k) * N + n0 + c8;
        float4 a = *(const float4*)f, b = *(const float4*)(f + 4);
        u16 vv[8] = {f2b(a.x), f2b(a.y), f2b(a.z), f2b(a.w),
                     f2b(b.x), f2b(b.y), f2b(b.z), f2b(b.w)};
#pragma unroll
        for (int j = 0; j < 8; j++) t[(c8 + j) * 66 + k] = vv[j];
    }
    __syncthreads();
#pragma unroll
    for (int h = 0; h < 2; h++) {
        int n = r + h * 32;
        short8 v;
#pragma unroll
        for (int j = 0; j < 8; j++) ((u16*)&v)[j] = t[n * 66 + c8 + j];
        *(short8*)(out + (size_t)(n0 + n) * 2048 + k0 + c8) = v;
    }
}

// ---------------- merged prep: 6 weight transposes + tables + mask + caches + cvt -----
// gx < 3072: weight transposes (formerly k_transpose6).
// gx >= 3072: tables/mask/caches/hv/ha conversion (formerly k_prep).
// Merged so both memory-bound phases co-execute instead of serializing on the stream.
__global__ void k_prep(const float* __restrict__ mask,
                       const float* __restrict__ kc, const float* __restrict__ vc,
                       const float* __restrict__ hv, const float* __restrict__ ha,
                       const float* __restrict__ w0, u16* __restrict__ o0,
                       const float* __restrict__ w1, u16* __restrict__ o1,
                       const float* __restrict__ w2, u16* __restrict__ o2,
                       const float* __restrict__ w3, u16* __restrict__ o3,
                       const float* __restrict__ w4, u16* __restrict__ o4,
                       const float* __restrict__ w5, u16* __restrict__ o5,
                       float* __restrict__ cosT, float* __restrict__ sinT,
                       u16* __restrict__ maskS, u16* __restrict__ K_all, u16* __restrict__ V_all,
                       u16* __restrict__ hv16, u16* __restrict__ ha16) {
    int gx = blockIdx.x, tid = threadIdx.x;
    if (gx < 3072) {
        if (gx < 256)        transpose_body(w0, o0, 512,  gx & 7,  gx >> 3);
        else if (gx < 512)   { int g = gx - 256;  transpose_body(w1, o1, 512,  g & 7,  g >> 3); }
        else if (gx < 768)   { int g = gx - 512;  transpose_body(w2, o2, 512,  g & 7,  g >> 3); }
        else if (gx < 1024)  { int g = gx - 768;  transpose_body(w3, o3, 512,  g & 7,  g >> 3); }
        else if (gx < 2048)  { int g = gx - 1024; transpose_body(w4, o4, 2048, g & 31, g >> 5); }
        else                 { int g = gx - 2048; transpose_body(w5, o5, 2048, g & 31, g >> 5); }
        return;
    }
    int bx = gx - 3072;
    if (bx < 336) {
        int i = bx * 256 + tid;
        if (i < STOT * 64) {
            int p = i >> 6, j = i & 63;
            float inv = __expf(-(float)j * (9.210340371976184f / 64.0f));  // 10000^(-j/64)
            float ang = (float)p * inv;
            cosT[i] = cosf(ang);
            sinT[i] = sinf(ang);
        }
    } else if (bx < 1680) {
        int i = (bx - 336) * 256 + tid;   // 344064 = 1344*256 exact
        int b = i / (SQA * STOT);
        int r = i % (SQA * STOT);
        size_t s = (size_t)b * SQTOT * STOT + (size_t)SQV * STOT + r;
        maskS[i] = f2b(mask[s]);
    } else if (bx < 1936) {
        int i = (bx - 1680) * 256 + tid;  // 65536 groups of 8
        int e = i * 8;
        int bk = e / (SCACHE * HD);
        int off = e % (SCACHE * HD);
        size_t dst = (size_t)bk * STOT * HD + off;
        const float* fk = kc + e;
        const float* fv = vc + e;
        u16 tk[8], tv[8];
#pragma unroll
        for (int j = 0; j < 8; j++) { tk[j] = f2b(fk[j]); tv[j] = f2b(fv[j]); }
        *(short8*)(K_all + dst) = *(short8*)tk;
        *(short8*)(V_all + dst) = *(short8*)tv;
    } else if (bx < 6032) {
        int i = (bx - 1936) * 256 + tid;  // 1,048,576 groups of 8
        int e = i * 8;
        const float* f = hv + e;
        float4 a = *(const float4*)f, b = *(const float4*)(f + 4);
        u16 t[8] = {f2b(a.x), f2b(a.y), f2b(a.z), f2b(a.w),
                    f2b(b.x), f2b(b.y), f2b(b.z), f2b(b.w)};
        *(short8*)(hv16 + e) = *(short8*)t;
    } else {
        int i = (bx - 6032) * 256 + tid;  // 65,536 groups of 8
        int e = i * 8;
        const float* f = ha + e;
        float4 a = *(const float4*)f, b = *(const float4*)(f + 4);
        u16 t[8] = {f2b(a.x), f2b(a.y), f2b(a.z), f2b(a.w),
                    f2b(b.x), f2b(b.y), f2b(b.z), f2b(b.w)};
        *(short8*)(ha16 + e) = *(short8*)t;
    }
}

// ---------------- fused QKV GEMM: global_load_lds + dbuf + counted vmcnt --------------
// grid (64, 10):
//   by<8:  vlm K/V proj: A=hv16[4096][2048], BM=64, by<4 -> K head by, else V head by-4.
//   by>=8: act Q/K/V proj: g=(by-8)*64+bx in [0,96): m0=(g&3)*64, ny=g>>2.
// K-loop (m97/T3-T4 structure): tile kb+1 staged asynchronously into the other LDS
// buffer via global_load_lds; s_waitcnt vmcnt(6) keeps those 6 loads in flight across
// the barrier (never drains to 0 mid-loop). LDS is linear (gload_lds requirement);
// bank conflicts avoided rule-#21 style: inverse-XOR-swizzled global SOURCE address
// (byte ^= (row&7)<<4 within the 128B row) + same XOR on the ds_read side.
__global__ __launch_bounds__(256) void k_gemm_qkv(
    const u16* __restrict__ Avlm, const u16* __restrict__ Aact,
    const u16* __restrict__ WkvT, const u16* __restrict__ WvvT,
    const u16* __restrict__ WqaT, const u16* __restrict__ WkaT, const u16* __restrict__ WvaT,
    const int* __restrict__ pos_vlm, const int* __restrict__ pos_act,
    const float* __restrict__ cosT, const float* __restrict__ sinT,
    u16* __restrict__ Qbuf, u16* __restrict__ K_all, u16* __restrict__ V_all) {
    // per buffer: A 64x64 u16 (4096) + B 128x64 u16 (8192) = 12288 u16; double-buffered.
    __shared__ __align__(16) u16 smem[2 * 12288];
    int tid = threadIdx.x;
    int w = tid >> 6, lane = tid & 63;
    int la = lane & 15, lg = lane >> 4;
    int wm = (w & 1) * 32;
    int c2 = w >> 1;
    int ntab[4] = {c2 * 2, c2 * 2 + 1, c2 * 2 + 4, c2 * 2 + 5};

    const u16* A; const u16* Bt; int m0, n0;
    int path;                 // 0 = vlm-K, 1 = vlm-V, 2 = act-Q, 3 = act-K, 4 = act-V
    int kv_or_head = 0;
    if (blockIdx.y < 8) {
        int by = blockIdx.y;
        m0 = blockIdx.x * 64;
        A = Avlm;
        path = (by < 4) ? 0 : 1;
        kv_or_head = by & 3;
        n0 = kv_or_head * 128;
        Bt = (path == 0) ? WkvT : WvvT;
    } else {
        int g = (blockIdx.y - 8) * 64 + blockIdx.x;
        if (g >= 96) return;
        m0 = (g & 3) * 64;
        int ny = g >> 2;
        A = Aact;
        if (ny < 16)      { path = 2; kv_or_head = ny;      Bt = WqaT; n0 = ny * 128; }
        else if (ny < 20) { path = 3; kv_or_head = ny - 16; Bt = WkaT; n0 = (ny - 16) * 128; }
        else              { path = 4; kv_or_head = ny - 20; Bt = WvaT; n0 = (ny - 20) * 128; }
    }

    f32x4 acc[2][4];
#pragma unroll
    for (int i = 0; i < 2; i++)
#pragma unroll
        for (int j = 0; j < 4; j++) acc[i][j] = (f32x4){0.f, 0.f, 0.f, 0.f};

    // staging geometry: per-issue flat byte f = tid*16 + h*4096; row = f>>7 (128B rows)
    int srow = tid >> 3;                                 // + h*32
    int scsrc = (((tid & 7) * 16) ^ ((srow & 7) << 4)) >> 1;   // swizzled src col (u16)

#define STAGE_QKV(CB, KB) do {                                                        \
        u16* Ab_ = smem + (CB) * 12288;                                               \
        u16* Bb_ = Ab_ + 4096;                                                        \
        _Pragma("unroll")                                                             \
        for (int h = 0; h < 2; h++)                                                   \
            gload16(A + (size_t)(m0 + srow + h * 32) * DMODEL + (KB) + scsrc,         \
                    Ab_ + h * 2048 + w * 512);                                        \
        _Pragma("unroll")                                                             \
        for (int h = 0; h < 4; h++)                                                   \
            gload16(Bt + (size_t)(n0 + srow + h * 32) * DMODEL + (KB) + scsrc,        \
                    Bb_ + h * 2048 + w * 512);                                        \
    } while (0)

    STAGE_QKV(0, 0);
    int cur = 0;
    int sw = (la & 7) << 3;     // read-side XOR swizzle (u16 units); row&7 == la&7
    for (int kb = 0; kb < DMODEL; kb += 64) {
        if (kb + 64 < DMODEL) {
            STAGE_QKV(cur ^ 1, kb + 64);
            asm volatile("s_waitcnt vmcnt(6)" ::: "memory");  // current tile landed
        } else {
            asm volatile("s_waitcnt vmcnt(0)" ::: "memory");
        }
        __builtin_amdgcn_s_barrier();
        asm volatile("" ::: "memory");   // keep ds_reads below the barrier
        const u16* Ac = smem + cur * 12288;
        const u16* Bc = Ac + 4096;
#pragma unroll
        for (int kk = 0; kk < 2; kk++) {
            short8 af[2], bf[4];
            int cc = (kk * 32 + lg * 8) ^ sw;
#pragma unroll
            for (int mt = 0; mt < 2; mt++)
                af[mt] = *(const short8*)&Ac[(wm + mt * 16 + la) * 64 + cc];
#pragma unroll
            for (int nt = 0; nt < 4; nt++)
                bf[nt] = *(const short8*)&Bc[(ntab[nt] * 16 + la) * 64 + cc];
#pragma unroll
            for (int mt = 0; mt < 2; mt++)
#pragma unroll
                for (int nt = 0; nt < 4; nt++)
                    acc[mt][nt] = __builtin_amdgcn_mfma_f32_16x16x32_bf16(af[mt], bf[nt], acc[mt][nt], 0, 0, 0);
        }
        __builtin_amdgcn_s_barrier();
        cur ^= 1;
    }
#undef STAGE_QKV

#pragma unroll
    for (int mt = 0; mt < 2; mt++) {
#pragma unroll
        for (int r = 0; r < 4; r++) {
            int gm = m0 + wm + mt * 16 + lg * 4 + r;
            if (path <= 1) {                       // vlm K/V
                int b = gm >> 10, s = gm & 1023;
                size_t base = ((size_t)(b * NKV + kv_or_head) * STOT + SCACHE + s) * HD;
                if (path == 0) {
                    int pos = pos_vlm[gm];
#pragma unroll
                    for (int i = 0; i < 2; i++) {
                        int dlo = ntab[i] * 16 + la;  // in [0,64)
                        float x1 = acc[mt][i][r], x2 = acc[mt][i + 2][r];
                        float cs = cosT[pos * 64 + dlo], sn = sinT[pos * 64 + dlo];
                        K_all[base + dlo]      = f2b(x1 * cs - x2 * sn);
                        K_all[base + dlo + 64] = f2b(x2 * cs + x1 * sn);
                    }
                } else {
#pragma unroll
                    for (int i = 0; i < 4; i++) V_all[base + ntab[i] * 16 + la] = f2b(acc[mt][i][r]);
                }
            } else {                               // action Q/K/V
                int b = gm >> 6, s = gm & 63;
                if (path == 2) {
                    int pos = pos_act[gm];
                    size_t qb = ((size_t)(b * NH + kv_or_head) * SQA + s) * HD;
#pragma unroll
                    for (int i = 0; i < 2; i++) {
                        int dlo = ntab[i] * 16 + la;
                        float x1 = acc[mt][i][r], x2 = acc[mt][i + 2][r];
                        float cs = cosT[pos * 64 + dlo], sn = sinT[pos * 64 + dlo];
                        Qbuf[qb + dlo]      = f2b(x1 * cs - x2 * sn);
                        Qbuf[qb + dlo + 64] = f2b(x2 * cs + x1 * sn);
                    }
                } else if (path == 3) {
                    int pos = pos_act[gm];
                    size_t base = ((size_t)(b * NKV + kv_or_head) * STOT + SCACHE + SQV + s) * HD;
#pragma unroll
                    for (int i = 0; i < 2; i++) {
                        int dlo = ntab[i] * 16 + la;
                        float x1 = acc[mt][i][r], x2 = acc[mt][i + 2][r];
                        float cs = cosT[pos * 64 + dlo], sn = sinT[pos * 64 + dlo];
                        K_all[base + dlo]      = f2b(x1 * cs - x2 * sn);
                        K_all[base + dlo + 64] = f2b(x2 * cs + x1 * sn);
                    }
                } else {
                    size_t base = ((size_t)(b * NKV + kv_or_head) * STOT + SCACHE + SQV + s) * HD;
#pragma unroll
                    for (int i = 0; i < 4; i++) V_all[base + ntab[i] * 16 + la] = f2b(acc[mt][i][r]);
                }
            }
        }
    }
}

// ---------------- split-K flash attention: grid (NH, BB, NSPLIT) ----------------------
__global__ __launch_bounds__(256) void k_attn_split(
    const u16* __restrict__ Qbuf, const u16* __restrict__ K_all, const u16* __restrict__ V_all,
    const u16* __restrict__ maskS, u16* __restrict__ po, float* __restrict__ pml) {
    int h = blockIdx.x, b = blockIdx.y, p = blockIdx.z;
    int bh = b * NH + h;
    int kvh = h >> 2;
    const u16* Kb = K_all + (size_t)(b * NKV + kvh) * STOT * HD;
    const u16* Vb = V_all + (size_t)(b * NKV + kvh) * STOT * HD;
    const u16* Qb = Qbuf + (size_t)bh * SQA * HD;
    int tid = threadIdx.x, w = tid >> 6, lane = tid & 63;
    int la = lane & 15, lg = lane >> 4;
    __shared__ __align__(16) u16 Ks[64 * 136];
    __shared__ __align__(16) u16 Vs[64 * 130];
    __shared__ __align__(16) u16 Ps[4][16 * 72];
    short8 qf[4];
#pragma unroll
    for (int kk = 0; kk < 4; kk++)
        qf[kk] = *(const short8*)(Qb + (size_t)(w * 16 + la) * HD + kk * 32 + lg * 8);
    f32x4 o_acc[8];
#pragma unroll
    for (int nt = 0; nt < 8; nt++) o_acc[nt] = (f32x4){0.f, 0.f, 0.f, 0.f};
    float m_run[4], l_run[4];
#pragma unroll
    for (int r = 0; r < 4; r++) { m_run[r] = -3e38f; l_run[r] = 0.f; }
    int vr = tid >> 4;           // [0,16)
    int vc = (tid & 15) * 8;     // [0,128)
    const float scl = 0.08838834764831845f;  // 1/sqrt(128)
    for (int c = 0; c < 3; c++) {
        int g = p * 3 + c;       // global 64-key chunk
#pragma unroll
        for (int hh = 0; hh < 4; hh++) {
            int key = vr + hh * 16;
            *(short8*)&Ks[key * 136 + vc] = *(const short8*)(Kb + (size_t)(g * 64 + key) * HD + vc);
            short8 vv = *(const short8*)(Vb + (size_t)(g * 64 + key) * HD + vc);
            unsigned int* d32 = (unsigned int*)&Vs[key * 130 + vc];
#pragma unroll
            for (int q2 = 0; q2 < 4; q2++) d32[q2] = ((unsigned int*)&vv)[q2];
        }
        __syncthreads();
        f32x4 s_acc[4];
#pragma unroll
        for (int nt = 0; nt < 4; nt++) s_acc[nt] = (f32x4){0.f, 0.f, 0.f, 0.f};
#pragma unroll
        for (int kk = 0; kk < 4; kk++) {
#pragma unroll
            for (int nt = 0; nt < 4; nt++) {
                short8 kf = *(const short8*)&Ks[(nt * 16 + la) * 136 + kk * 32 + lg * 8];
                s_acc[nt] = __builtin_amdgcn_mfma_f32_16x16x32_bf16(qf[kk], kf, s_acc[nt], 0, 0, 0);
            }
        }
        float sc[4][4];
#pragma unroll
        for (int nt = 0; nt < 4; nt++) {
            int key = g * 64 + nt * 16 + la;
#pragma unroll
            for (int r = 0; r < 4; r++) {
                int sq = w * 16 + lg * 4 + r;
                float sv = s_acc[nt][r] * scl;
                // fast stable tanh: tanh(x) = sign(x)*(1-e^{-2|x|})/(1+e^{-2|x|})
                float x = sv * 0.02f;
                float t = __expf(-2.0f * fabsf(x));
                float th = __fdividef(1.0f - t, 1.0f + t);
                sv = copysignf(th, x) * 50.0f;
                sv += b2f(maskS[((size_t)(b * SQA + sq)) * STOT + key]);
                sc[nt][r] = sv;
            }
        }
#pragma unroll
        for (int r = 0; r < 4; r++) {
            float mx = fmaxf(fmaxf(sc[0][r], sc[1][r]), fmaxf(sc[2][r], sc[3][r]));
#pragma unroll
            for (int sh = 1; sh < 16; sh <<= 1) mx = fmaxf(mx, __shfl_xor(mx, sh, 64));
            float mn = fmaxf(m_run[r], mx);
            float alpha = __expf(m_run[r] - mn);
            m_run[r] = mn;
            float rowsum = 0.f;
#pragma unroll
            for (int nt = 0; nt < 4; nt++) {
                float pv = __expf(sc[nt][r] - mn);
                Ps[w][(lg * 4 + r) * 72 + nt * 16 + la] = f2b(pv);
                rowsum += pv;
            }
#pragma unroll
            for (int sh = 1; sh < 16; sh <<= 1) rowsum += __shfl_xor(rowsum, sh, 64);
            l_run[r] = l_run[r] * alpha + rowsum;
#pragma unroll
            for (int nt = 0; nt < 8; nt++) o_acc[nt][r] *= alpha;
        }
        __syncthreads();
#pragma unroll
        for (int kk = 0; kk < 2; kk++) {
            short8 pf = *(const short8*)&Ps[w][la * 72 + kk * 32 + lg * 8];
#pragma unroll
            for (int nt = 0; nt < 8; nt++) {
                short8 vf;
#pragma unroll
                for (int j = 0; j < 8; j++) ((u16*)&vf)[j] = Vs[(kk * 32 + lg * 8 + j) * 130 + nt * 16 + la];
                o_acc[nt] = __builtin_amdgcn_mfma_f32_16x16x32_bf16(pf, vf, o_acc[nt], 0, 0, 0);
            }
        }
        __syncthreads();
    }
#pragma unroll
    for (int nt = 0; nt < 8; nt++) {
#pragma unroll
        for (int r = 0; r < 4; r++) {
            int sq = w * 16 + lg * 4 + r;
            po[(((size_t)p * 64 + bh) * 64 + sq) * 128 + nt * 16 + la] = f2b(o_acc[nt][r]);
        }
    }
    if (la == 0) {
#pragma unroll
        for (int r = 0; r < 4; r++) {
            int sq = w * 16 + lg * 4 + r;
            size_t mlb = (((size_t)p * 64 + bh) * 64 + sq) * 2;
            pml[mlb] = m_run[r];
            pml[mlb + 1] = l_run[r];
        }
    }
}

// ---------------- attention reduce: combine NSPLIT partials -> AO bf16 ----------------
__global__ __launch_bounds__(256) void k_attn_red(
    const u16* __restrict__ po, const float* __restrict__ pml, u16* __restrict__ AO) {
    int h = blockIdx.x, b = blockIdx.y;
    int bh = b * NH + h;
    __shared__ float wgt[NSPLIT][64];
    int tid = threadIdx.x;
    if (tid < 64) {
        int q = tid;
        float m[NSPLIT], l[NSPLIT], M = -3e38f;
#pragma unroll
        for (int p = 0; p < NSPLIT; p++) {
            size_t mlb = (((size_t)p * 64 + bh) * 64 + q) * 2;
            m[p] = pml[mlb]; l[p] = pml[mlb + 1];
            M = fmaxf(M, m[p]);
        }
        float L = 0.f;
#pragma unroll
        for (int p = 0; p < NSPLIT; p++) L += l[p] * __expf(m[p] - M);
        float inv = 1.0f / L;
#pragma unroll
        for (int p = 0; p < NSPLIT; p++) wgt[p][q] = __expf(m[p] - M) * inv;
    }
    __syncthreads();
    for (int e = tid; e < 64 * 128; e += 256) {
        int q = e >> 7, d = e & 127;
        float s = 0.f;
#pragma unroll
        for (int p = 0; p < NSPLIT; p++)
            s += b2f(po[(((size_t)p * 64 + bh) * 64 + q) * 128 + d]) * wgt[p][q];
        AO[((size_t)(b * SQA + q)) * 2048 + h * HD + d] = f2b(s);
    }
}

// ---------------- final GEMM: AO[256][2048] @ WoT -> out f32 --------------------------
// Same gload_lds + dbuf + counted-vmcnt structure as k_gemm_qkv (64x64 tiles, 4 loads).
__global__ __launch_bounds__(256) void k_gemm_out(
    const u16* __restrict__ A, const u16* __restrict__ WoT, float* __restrict__ out) {
    __shared__ __align__(16) u16 smem[2 * 8192];   // per buf: A 4096 + B 4096 u16
    int m0 = blockIdx.x * 64, n0 = blockIdx.y * 64;
    int tid = threadIdx.x;
    int w = tid >> 6, lane = tid & 63;
    int la = lane & 15, lg = lane >> 4;
    int wm = (w & 1) * 32, wn = (w >> 1) * 32;
    f32x4 acc[2][2];
#pragma unroll
    for (int i = 0; i < 2; i++)
#pragma unroll
        for (int j = 0; j < 2; j++) acc[i][j] = (f32x4){0.f, 0.f, 0.f, 0.f};

    int srow = tid >> 3;
    int scsrc = (((tid & 7) * 16) ^ ((srow & 7) << 4)) >> 1;

#define STAGE_OUT(CB, KB) do {                                                        \
        u16* Ab_ = smem + (CB) * 8192;                                                \
        u16* Bb_ = Ab_ + 4096;                                                        \
        _Pragma("unroll")                                                             \
        for (int h = 0; h < 2; h++)                                                   \
            gload16(A + (size_t)(m0 + srow + h * 32) * DMODEL + (KB) + scsrc,         \
                    Ab_ + h * 2048 + w * 512);                                        \
        _Pragma("unroll")                                                             \
        for (int h = 0; h < 2; h++)                                                   \
            gload16(WoT + (size_t)(n0 + srow + h * 32) * DMODEL + (KB) + scsrc,       \
                    Bb_ + h * 2048 + w * 512);                                        \
    } while (0)

    STAGE_OUT(0, 0);
    int cur = 0;
    int sw = (la & 7) << 3;
    for (int kb = 0; kb < DMODEL; kb += 64) {
        if (kb + 64 < DMODEL) {
            STAGE_OUT(cur ^ 1, kb + 64);
            asm volatile("s_waitcnt vmcnt(4)" ::: "memory");
        } else {
            asm volatile("s_waitcnt vmcnt(0)" ::: "memory");
        }
        __builtin_amdgcn_s_barrier();
        asm volatile("" ::: "memory");
        const u16* Ac = smem + cur * 8192;
        const u16* Bc = Ac + 4096;
#pragma unroll
        for (int kk = 0; kk < 2; kk++) {
            short8 af[2], bf[2];
            int cc = (kk * 32 + lg * 8) ^ sw;
#pragma unroll
            for (int mt = 0; mt < 2; mt++) af[mt] = *(const short8*)&Ac[(wm + mt * 16 + la) * 64 + cc];
#pragma unroll
            for (int nt = 0; nt < 2; nt++) bf[nt] = *(const short8*)&Bc[(wn + nt * 16 + la) * 64 + cc];
#pragma unroll
            for (int mt = 0; mt < 2; mt++)
#pragma unroll
                for (int nt = 0; nt < 2; nt++)
                    acc[mt][nt] = __builtin_amdgcn_mfma_f32_16x16x32_bf16(af[mt], bf[nt], acc[mt][nt], 0, 0, 0);
        }
        __builtin_amdgcn_s_barrier();
        cur ^= 1;
    }
#undef STAGE_OUT

#pragma unroll
    for (int mt = 0; mt < 2; mt++) {
#pragma unroll
        for (int r = 0; r < 4; r++) {
            int gm = m0 + wm + mt * 16 + lg * 4 + r;
#pragma unroll
            for (int nt = 0; nt < 2; nt++)
                out[(size_t)gm * DMODEL + n0 + wn + nt * 16 + la] = acc[mt][nt][r];
        }
    }
}

extern "C" void kernel_launch(void* const* d_in, const int* in_sizes, int n_in,
                              void* d_out, int out_size, void* d_ws, size_t ws_size,
                              hipStream_t stream) {
    (void)in_sizes; (void)n_in; (void)out_size;
    const float* mask    = (const float*)d_in[0];
    const int*   pos_vlm = (const int*)d_in[1];
    const int*   pos_act = (const int*)d_in[2];
    const float* h_vlm   = (const float*)d_in[3];
    const float* h_act   = (const float*)d_in[4];
    const float* k_cache = (const float*)d_in[5];
    const float* v_cache = (const float*)d_in[6];
    // d_in[7] = Wq_vlm -- unused (only action-query outputs are returned)
    const float* Wk_vlm  = (const float*)d_in[8];
    const float* Wv_vlm  = (const float*)d_in[9];
    const float* Wq_act  = (const float*)d_in[10];
    const float* Wk_act  = (const float*)d_in[11];
    const float* Wv_act  = (const float*)d_in[12];
    const float* Wo_act  = (const float*)d_in[13];

    const size_t NEED = 65273856;
    if (ws_size < NEED) return;
    char* ws = (char*)d_ws;
    float* cosT  = (float*)(ws + 0);          // 344064
    float* sinT  = (float*)(ws + 344064);     // 344064
    u16* K_all   = (u16*)(ws + 688128);       // 5505024
    u16* V_all   = (u16*)(ws + 6193152);      // 5505024
    u16* Qbuf    = (u16*)(ws + 11698176);     // 1048576
    u16* AO      = (u16*)(ws + 12746752);     // 1048576
    u16* WkvT    = (u16*)(ws + 13795328);     // 2097152
    u16* WvvT    = (u16*)(ws + 15892480);     // 2097152
    u16* WqaT    = (u16*)(ws + 17989632);     // 8388608
    u16* WkaT    = (u16*)(ws + 26378240);     // 2097152
    u16* WvaT    = (u16*)(ws + 28475392);     // 2097152
    u16* WoT     = (u16*)(ws + 30572544);     // 8388608
    u16* po      = (u16*)(ws + 38961152);     // 7340032
    float* pml   = (float*)(ws + 46301184);   // 458752
    u16* maskS   = (u16*)(ws + 46759936);     // 688128
    u16* hv16    = (u16*)(ws + 47448064);     // 16777216
    u16* ha16    = (u16*)(ws + 64225280);     // 1048576  -> end 65273856

    // merged transposes + prep: 3072 transpose blocks + 6288 prep blocks
    hipLaunchKernelGGL(k_prep, dim3(9360), dim3(256), 0, stream,
                       mask, k_cache, v_cache, h_vlm, h_act,
                       Wk_vlm, WkvT, Wv_vlm, WvvT, Wk_act, WkaT, Wv_act, WvaT,
                       Wq_act, WqaT, Wo_act, WoT,
                       cosT, sinT, maskS, K_all, V_all, hv16, ha16);
    hipLaunchKernelGGL(k_gemm_qkv, dim3(64, 10), dim3(256), 0, stream,
                       hv16, ha16, WkvT, WvvT, WqaT, WkaT, WvaT,
                       pos_vlm, pos_act, cosT, sinT, Qbuf, K_all, V_all);
    hipLaunchKernelGGL(k_attn_split, dim3(16, 4, NSPLIT), dim3(256), 0, stream,
                       Qbuf, K_all, V_all, maskS, po, pml);
    hipLaunchKernelGGL(k_attn_red, dim3(16, 4), dim3(256), 0, stream, po, pml, AO);
    hipLaunchKernelGGL(k_gemm_out, dim3(4, 32), dim3(256), 0, stream, AO, WoT, (float*)d_out);
}

// Round 2
// 233.623 us; speedup vs baseline: 1.0845x; 1.0235x over previous
//
#include <hip/hip_runtime.h>
#include <cmath>

#define NH 16
#define NKV 4
#define HD 128
#define DMODEL 2048
#define BB 4
#define SQV 1024
#define SQA 64
#define SCACHE 256
#define STOT 1344   // SCACHE + SQV + SQA
#define SQTOT 1088  // SQV + SQA
#define NSPLIT 7    // attention K-partitions (192 keys = 3 chunks each)

typedef unsigned short u16;
typedef __attribute__((ext_vector_type(8))) short short8;
typedef __attribute__((ext_vector_type(4))) float f32x4;

__device__ __forceinline__ float b2f(u16 u) {
    union { float f; unsigned int i; } x; x.i = ((unsigned int)u) << 16; return x.f;
}
__device__ __forceinline__ u16 f2b(float f) {
    unsigned int x = __float_as_uint(f);
    x = x + 0x7fffu + ((x >> 16) & 1u);   // RNE
    return (u16)(x >> 16);
}

// async global->LDS, 16B per lane. LDS dest is wave-uniform base + lane*16 (linear).
__device__ __forceinline__ void gload16(const void* g, void* l) {
    __builtin_amdgcn_global_load_lds((const __attribute__((address_space(1))) void*)g,
                                     (__attribute__((address_space(3))) void*)l, 16, 0, 0);
}

// ---------------- transpose body: fp32 [2048][N] tile -> bf16 [N][2048] ---------------
__device__ __forceinline__ void transpose_body(const float* in, u16* out, int N,
                                               int bx, int by) {
    __shared__ __align__(16) u16 t[64 * 66];
    int n0 = bx * 64, k0 = by * 64;
    int tid = threadIdx.x;
    int r = tid >> 3;
    int c8 = (tid & 7) * 8;
#pragma unroll
    for (int h = 0; h < 2; h++) {
        int k = r + h * 32;
        const float* f = in + (size_t)(k0 + k) * N + n0 + c8;
        float4 a = *(const float4*)f, b = *(const float4*)(f + 4);
        u16 vv[8] = {f2b(a.x), f2b(a.y), f2b(a.z), f2b(a.w),
                     f2b(b.x), f2b(b.y), f2b(b.z), f2b(b.w)};
#pragma unroll
        for (int j = 0; j < 8; j++) t[(c8 + j) * 66 + k] = vv[j];
    }
    __syncthreads();
#pragma unroll
    for (int h = 0; h < 2; h++) {
        int n = r + h * 32;
        short8 v;
#pragma unroll
        for (int j = 0; j < 8; j++) ((u16*)&v)[j] = t[n * 66 + c8 + j];
        *(short8*)(out + (size_t)(n0 + n) * 2048 + k0 + c8) = v;
    }
}

// ------------- v_cache transpose: fp32 [key 256][d 128] -> bf16 VT [d][STOT keys] -----
__device__ __forceinline__ void transpose_vc(const float* vc, u16* VT, int idx) {
    __shared__ __align__(16) u16 tv[64 * 66];
    int bkv = idx >> 3, t8 = idx & 7;
    int key0 = (t8 >> 1) * 64, d0 = (t8 & 1) * 64;
    const float* in = vc + ((size_t)bkv * SCACHE + key0) * HD + d0;
    u16* out = VT + ((size_t)bkv * HD + d0) * STOT + key0;
    int tid = threadIdx.x;
    int r = tid >> 3, c8 = (tid & 7) * 8;
#pragma unroll
    for (int h = 0; h < 2; h++) {
        int k = r + h * 32;                     // key row
        const float* f = in + (size_t)k * HD + c8;
        float4 a = *(const float4*)f, b = *(const float4*)(f + 4);
        u16 vv[8] = {f2b(a.x), f2b(a.y), f2b(a.z), f2b(a.w),
                     f2b(b.x), f2b(b.y), f2b(b.z), f2b(b.w)};
#pragma unroll
        for (int j = 0; j < 8; j++) tv[(c8 + j) * 66 + k] = vv[j];
    }
    __syncthreads();
#pragma unroll
    for (int h = 0; h < 2; h++) {
        int d = r + h * 32;                     // d row of VT
        short8 v;
#pragma unroll
        for (int j = 0; j < 8; j++) ((u16*)&v)[j] = tv[d * 66 + c8 + j];
        *(short8*)(out + (size_t)d * STOT + c8) = v;
    }
}

// ---------------- merged prep: weight transposes + tables + mask + caches + cvt -------
__global__ void k_prep(const float* __restrict__ mask,
                       const float* __restrict__ kc, const float* __restrict__ vc,
                       const float* __restrict__ hv, const float* __restrict__ ha,
                       const float* __restrict__ w0, u16* __restrict__ o0,
                       const float* __restrict__ w1, u16* __restrict__ o1,
                       const float* __restrict__ w2, u16* __restrict__ o2,
                       const float* __restrict__ w3, u16* __restrict__ o3,
                       const float* __restrict__ w4, u16* __restrict__ o4,
                       const float* __restrict__ w5, u16* __restrict__ o5,
                       float* __restrict__ cosT, float* __restrict__ sinT,
                       u16* __restrict__ maskS, u16* __restrict__ K_all, u16* __restrict__ VT_all,
                       u16* __restrict__ hv16, u16* __restrict__ ha16) {
    int gx = blockIdx.x, tid = threadIdx.x;
    if (gx < 3072) {
        if (gx < 256)        transpose_body(w0, o0, 512,  gx & 7,  gx >> 3);
        else if (gx < 512)   { int g = gx - 256;  transpose_body(w1, o1, 512,  g & 7,  g >> 3); }
        else if (gx < 768)   { int g = gx - 512;  transpose_body(w2, o2, 512,  g & 7,  g >> 3); }
        else if (gx < 1024)  { int g = gx - 768;  transpose_body(w3, o3, 512,  g & 7,  g >> 3); }
        else if (gx < 2048)  { int g = gx - 1024; transpose_body(w4, o4, 2048, g & 31, g >> 5); }
        else                 { int g = gx - 2048; transpose_body(w5, o5, 2048, g & 31, g >> 5); }
        return;
    }
    int bx = gx - 3072;
    if (bx < 336) {
        int i = bx * 256 + tid;
        if (i < STOT * 64) {
            int p = i >> 6, j = i & 63;
            float inv = __expf(-(float)j * (9.210340371976184f / 64.0f));  // 10000^(-j/64)
            float ang = (float)p * inv;
            cosT[i] = cosf(ang);
            sinT[i] = sinf(ang);
        }
    } else if (bx < 1680) {
        int i = (bx - 336) * 256 + tid;   // 344064 = 1344*256 exact
        int b = i / (SQA * STOT);
        int r = i % (SQA * STOT);
        size_t s = (size_t)b * SQTOT * STOT + (size_t)SQV * STOT + r;
        maskS[i] = f2b(mask[s]);
    } else if (bx < 1936) {
        int i = (bx - 1680) * 256 + tid;  // 65536 groups of 8 (K cache only)
        int e = i * 8;
        int bk = e / (SCACHE * HD);
        int off = e % (SCACHE * HD);
        size_t dst = (size_t)bk * STOT * HD + off;
        const float* fk = kc + e;
        u16 tk[8];
#pragma unroll
        for (int j = 0; j < 8; j++) tk[j] = f2b(fk[j]);
        *(short8*)(K_all + dst) = *(short8*)tk;
    } else if (bx < 6032) {
        int i = (bx - 1936) * 256 + tid;  // 1,048,576 groups of 8
        int e = i * 8;
        const float* f = hv + e;
        float4 a = *(const float4*)f, b = *(const float4*)(f + 4);
        u16 t[8] = {f2b(a.x), f2b(a.y), f2b(a.z), f2b(a.w),
                    f2b(b.x), f2b(b.y), f2b(b.z), f2b(b.w)};
        *(short8*)(hv16 + e) = *(short8*)t;
    } else if (bx < 6288) {
        int i = (bx - 6032) * 256 + tid;  // 65,536 groups of 8
        int e = i * 8;
        const float* f = ha + e;
        float4 a = *(const float4*)f, b = *(const float4*)(f + 4);
        u16 t[8] = {f2b(a.x), f2b(a.y), f2b(a.z), f2b(a.w),
                    f2b(b.x), f2b(b.y), f2b(b.z), f2b(b.w)};
        *(short8*)(ha16 + e) = *(short8*)t;
    } else {
        transpose_vc(vc, VT_all, bx - 6288);   // 128 blocks
    }
}

// ---------------- fused QKV GEMM: 128x128 tiles, gload_lds dbuf, counted vmcnt --------
// 1D grid 304: bid<256 -> vlm K/V proj (A=hv16[4096][2048]): m0=(bid&31)*128, yy=bid>>5,
//   yy<4 -> K head yy, else V head yy-4.  bid>=256 -> act (A=ha16[256][2048]):
//   g=bid-256: m0=(g&1)*128, ny=g>>1: Q(ny<16) / K(16..19) / V(20..23).
// 4 waves in 2(m)x2(n-interleave): wave m-row (w&1)*64, n-frags via ntab so each wave
// holds rope pairs (col, col+64) in-register.  V-paths write VT_all[d][key] (transposed)
// for the attention PV B-operand.
__global__ __launch_bounds__(256) void k_gemm_qkv(
    const u16* __restrict__ Avlm, const u16* __restrict__ Aact,
    const u16* __restrict__ WkvT, const u16* __restrict__ WvvT,
    const u16* __restrict__ WqaT, const u16* __restrict__ WkaT, const u16* __restrict__ WvaT,
    const int* __restrict__ pos_vlm, const int* __restrict__ pos_act,
    const float* __restrict__ cosT, const float* __restrict__ sinT,
    u16* __restrict__ Qbuf, u16* __restrict__ K_all, u16* __restrict__ VT_all) {
    // per buffer: A 128x64 (8192 u16) + B 128x64 (8192 u16); double-buffered = 64 KiB.
    __shared__ __align__(16) u16 smem[2 * 16384];
    int tid = threadIdx.x;
    int w = tid >> 6, lane = tid & 63;
    int la = lane & 15, lg = lane >> 4;
    int wm = (w & 1) * 64;
    int c2 = w >> 1;
    int ntab[4] = {c2 * 2, c2 * 2 + 1, c2 * 2 + 4, c2 * 2 + 5};

    const u16* A; const u16* Bt; int m0, n0;
    int path;                 // 0 = vlm-K, 1 = vlm-V, 2 = act-Q, 3 = act-K, 4 = act-V
    int head;
    int bid = blockIdx.x;
    if (bid < 256) {
        m0 = (bid & 31) * 128;
        int yy = bid >> 5;
        path = (yy < 4) ? 0 : 1;
        head = yy & 3;
        n0 = head * 128;
        A = Avlm;
        Bt = (path == 0) ? WkvT : WvvT;
    } else {
        int g = bid - 256;
        m0 = (g & 1) * 128;
        int ny = g >> 1;
        A = Aact;
        if (ny < 16)      { path = 2; head = ny;      Bt = WqaT; n0 = ny * 128; }
        else if (ny < 20) { path = 3; head = ny - 16; Bt = WkaT; n0 = (ny - 16) * 128; }
        else              { path = 4; head = ny - 20; Bt = WvaT; n0 = (ny - 20) * 128; }
    }

    f32x4 acc[4][4];
#pragma unroll
    for (int i = 0; i < 4; i++)
#pragma unroll
        for (int j = 0; j < 4; j++) acc[i][j] = (f32x4){0.f, 0.f, 0.f, 0.f};

    // staging: dest flat byte = tid*16 + h*4096 -> row = h*32 + tid>>3 (128B rows)
    int srow = tid >> 3;
    int scsrc = (((tid & 7) * 16) ^ ((srow & 7) << 4)) >> 1;   // swizzled src col (u16)

#define STAGE_QKV(CB, KB) do {                                                        \
        u16* Ab_ = smem + (CB) * 16384;                                               \
        u16* Bb_ = Ab_ + 8192;                                                        \
        _Pragma("unroll")                                                             \
        for (int h = 0; h < 4; h++)                                                   \
            gload16(A + (size_t)(m0 + srow + h * 32) * DMODEL + (KB) + scsrc,         \
                    Ab_ + h * 2048 + tid * 8);                                        \
        _Pragma("unroll")                                                             \
        for (int h = 0; h < 4; h++)                                                   \
            gload16(Bt + (size_t)(n0 + srow + h * 32) * DMODEL + (KB) + scsrc,        \
                    Bb_ + h * 2048 + tid * 8);                                        \
    } while (0)

    STAGE_QKV(0, 0);
    int cur = 0;
    int swr = (la & 7) << 3;     // read-side XOR swizzle (u16 units); row&7 == la&7
    for (int kb = 0; kb < DMODEL; kb += 64) {
        if (kb + 64 < DMODEL) {
            STAGE_QKV(cur ^ 1, kb + 64);
            asm volatile("s_waitcnt vmcnt(8)" ::: "memory");  // current tile landed
        } else {
            asm volatile("s_waitcnt vmcnt(0)" ::: "memory");
        }
        __builtin_amdgcn_s_barrier();
        asm volatile("" ::: "memory");
        const u16* Ac = smem + cur * 16384;
        const u16* Bc = Ac + 8192;
#pragma unroll
        for (int kk = 0; kk < 2; kk++) {
            short8 af[4], bf[4];
            int cc = (kk * 32 + lg * 8) ^ swr;
#pragma unroll
            for (int mt = 0; mt < 4; mt++)
                af[mt] = *(const short8*)&Ac[(wm + mt * 16 + la) * 64 + cc];
#pragma unroll
            for (int nt = 0; nt < 4; nt++)
                bf[nt] = *(const short8*)&Bc[(ntab[nt] * 16 + la) * 64 + cc];
#pragma unroll
            for (int mt = 0; mt < 4; mt++)
#pragma unroll
                for (int nt = 0; nt < 4; nt++)
                    acc[mt][nt] = __builtin_amdgcn_mfma_f32_16x16x32_bf16(af[mt], bf[nt], acc[mt][nt], 0, 0, 0);
        }
        __builtin_amdgcn_s_barrier();
        cur ^= 1;
    }
#undef STAGE_QKV

#pragma unroll
    for (int mt = 0; mt < 4; mt++) {
#pragma unroll
        for (int r = 0; r < 4; r++) {
            int gm = m0 + wm + mt * 16 + lg * 4 + r;
            if (path <= 1) {                       // vlm K/V
                int b = gm >> 10, s = gm & 1023;
                if (path == 0) {
                    size_t base = ((size_t)(b * NKV + head) * STOT + SCACHE + s) * HD;
                    int pos = pos_vlm[gm];
#pragma unroll
                    for (int i = 0; i < 2; i++) {
                        int dlo = ntab[i] * 16 + la;  // in [0,64)
                        float x1 = acc[mt][i][r], x2 = acc[mt][i + 2][r];
                        float cs = cosT[pos * 64 + dlo], sn = sinT[pos * 64 + dlo];
                        K_all[base + dlo]      = f2b(x1 * cs - x2 * sn);
                        K_all[base + dlo + 64] = f2b(x2 * cs + x1 * sn);
                    }
                } else {
                    size_t vt = ((size_t)(b * NKV + head) * HD) * STOT + SCACHE + s;
#pragma unroll
                    for (int i = 0; i < 4; i++) {
                        int d = ntab[i] * 16 + la;    // in [0,128)
                        VT_all[vt + (size_t)d * STOT] = f2b(acc[mt][i][r]);
                    }
                }
            } else {                               // action Q/K/V
                int b = gm >> 6, s = gm & 63;
                if (path == 2) {
                    int pos = pos_act[gm];
                    size_t qb = ((size_t)(b * NH + head) * SQA + s) * HD;
#pragma unroll
                    for (int i = 0; i < 2; i++) {
                        int dlo = ntab[i] * 16 + la;
                        float x1 = acc[mt][i][r], x2 = acc[mt][i + 2][r];
                        float cs = cosT[pos * 64 + dlo], sn = sinT[pos * 64 + dlo];
                        Qbuf[qb + dlo]      = f2b(x1 * cs - x2 * sn);
                        Qbuf[qb + dlo + 64] = f2b(x2 * cs + x1 * sn);
                    }
                } else if (path == 3) {
                    int pos = pos_act[gm];
                    size_t base = ((size_t)(b * NKV + head) * STOT + SCACHE + SQV + s) * HD;
#pragma unroll
                    for (int i = 0; i < 2; i++) {
                        int dlo = ntab[i] * 16 + la;
                        float x1 = acc[mt][i][r], x2 = acc[mt][i + 2][r];
                        float cs = cosT[pos * 64 + dlo], sn = sinT[pos * 64 + dlo];
                        K_all[base + dlo]      = f2b(x1 * cs - x2 * sn);
                        K_all[base + dlo + 64] = f2b(x2 * cs + x1 * sn);
                    }
                } else {
                    size_t vt = ((size_t)(b * NKV + head) * HD) * STOT + SCACHE + SQV + s;
#pragma unroll
                    for (int i = 0; i < 4; i++) {
                        int d = ntab[i] * 16 + la;
                        VT_all[vt + (size_t)d * STOT] = f2b(acc[mt][i][r]);
                    }
                }
            }
        }
    }
}

// ---------------- split-K flash attention: grid (NH, BB, NSPLIT) ----------------------
// K staged row-major [64 key][128 d], Vt staged transposed [128 d][64 key]; both via
// gload_lds into linear XOR-swizzled buffers, double-buffered, counted vmcnt(8),
// 2 barriers/chunk.  PV B-operand is now ds_read_b128 (was 128 scalar u16 reads).
__global__ __launch_bounds__(256) void k_attn_split(
    const u16* __restrict__ Qbuf, const u16* __restrict__ K_all, const u16* __restrict__ VT_all,
    const u16* __restrict__ maskS, u16* __restrict__ po, float* __restrict__ pml) {
    int h = blockIdx.x, b = blockIdx.y, p = blockIdx.z;
    int bh = b * NH + h;
    int kvh = h >> 2;
    const u16* Kb  = K_all  + (size_t)(b * NKV + kvh) * STOT * HD;   // [key][d]
    const u16* VTb = VT_all + (size_t)(b * NKV + kvh) * HD * STOT;   // [d][key]
    const u16* Qb  = Qbuf + (size_t)bh * SQA * HD;
    int tid = threadIdx.x, w = tid >> 6, lane = tid & 63;
    int la = lane & 15, lg = lane >> 4;
    __shared__ __align__(16) u16 Ks[2][64 * 128];
    __shared__ __align__(16) u16 Vt[2][128 * 64];
    __shared__ __align__(16) u16 Ps[4][16 * 72];
    short8 qf[4];
#pragma unroll
    for (int kk = 0; kk < 4; kk++)
        qf[kk] = *(const short8*)(Qb + (size_t)(w * 16 + la) * HD + kk * 32 + lg * 8);
    f32x4 o_acc[8];
#pragma unroll
    for (int nt = 0; nt < 8; nt++) o_acc[nt] = (f32x4){0.f, 0.f, 0.f, 0.f};
    float m_run[4], l_run[4];
#pragma unroll
    for (int r = 0; r < 4; r++) { m_run[r] = -3e38f; l_run[r] = 0.f; }

    // K stage geometry: dest flat byte = tid*16 + h*4096 -> row = h*16 + tid>>4 (256B rows)
    int kr = tid >> 4;
    int ksw = (((tid & 15) * 16) ^ ((kr & 7) << 4)) >> 1;    // u16 units, in [0,128)
    // Vt stage geometry: row = h*32 + tid>>3 (128B rows)
    int vr = tid >> 3;
    int vsw = (((tid & 7) * 16) ^ ((vr & 7) << 4)) >> 1;     // u16 units, in [0,64)

#define ASTAGE(CB, G) do {                                                            \
        _Pragma("unroll")                                                             \
        for (int hh = 0; hh < 4; hh++)                                                \
            gload16(Kb + (size_t)((G) * 64 + kr + hh * 16) * HD + ksw,                \
                    &Ks[CB][hh * 2048 + tid * 8]);                                    \
        _Pragma("unroll")                                                             \
        for (int hh = 0; hh < 4; hh++)                                                \
            gload16(VTb + (size_t)(vr + hh * 32) * STOT + (G) * 64 + vsw,             \
                    &Vt[CB][hh * 2048 + tid * 8]);                                    \
    } while (0)

    ASTAGE(0, p * 3);
    int cur = 0;
    int swr = (la & 7) << 3;
    const float scl = 0.08838834764831845f;  // 1/sqrt(128)
    for (int c = 0; c < 3; c++) {
        int g = p * 3 + c;       // global 64-key chunk
        // preload this chunk's mask to regs BEFORE issuing next stage (keeps the
        // compiler's mask-wait from draining the staging queue)
        u16 mreg[4][4];
#pragma unroll
        for (int nt = 0; nt < 4; nt++)
#pragma unroll
            for (int r = 0; r < 4; r++)
                mreg[nt][r] = maskS[((size_t)(b * SQA + w * 16 + lg * 4 + r)) * STOT +
                                    g * 64 + nt * 16 + la];
        if (c < 2) {
            ASTAGE(cur ^ 1, g + 1);
            asm volatile("s_waitcnt vmcnt(8)" ::: "memory");
        } else {
            asm volatile("s_waitcnt vmcnt(0)" ::: "memory");
        }
        __builtin_amdgcn_s_barrier();
        asm volatile("" ::: "memory");
        // ---- QK^T ----
        f32x4 s_acc[4];
#pragma unroll
        for (int nt = 0; nt < 4; nt++) s_acc[nt] = (f32x4){0.f, 0.f, 0.f, 0.f};
        __builtin_amdgcn_s_setprio(1);
#pragma unroll
        for (int kk = 0; kk < 4; kk++) {
            int cc = (kk * 32 + lg * 8) ^ swr;
#pragma unroll
            for (int nt = 0; nt < 4; nt++) {
                short8 kf = *(const short8*)&Ks[cur][(nt * 16 + la) * 128 + cc];
                s_acc[nt] = __builtin_amdgcn_mfma_f32_16x16x32_bf16(qf[kk], kf, s_acc[nt], 0, 0, 0);
            }
        }
        __builtin_amdgcn_s_setprio(0);
        // ---- scores: scale, softclamp, mask ----
        float sc[4][4];
#pragma unroll
        for (int nt = 0; nt < 4; nt++) {
#pragma unroll
            for (int r = 0; r < 4; r++) {
                float sv = s_acc[nt][r] * scl;
                float x = sv * 0.02f;
                float t = __expf(-2.0f * fabsf(x));
                float th = __fdividef(1.0f - t, 1.0f + t);
                sv = copysignf(th, x) * 50.0f;
                sv += b2f(mreg[nt][r]);
                sc[nt][r] = sv;
            }
        }
        // ---- online softmax ----
#pragma unroll
        for (int r = 0; r < 4; r++) {
            float mx = fmaxf(fmaxf(sc[0][r], sc[1][r]), fmaxf(sc[2][r], sc[3][r]));
#pragma unroll
            for (int sh = 1; sh < 16; sh <<= 1) mx = fmaxf(mx, __shfl_xor(mx, sh, 64));
            float mn = fmaxf(m_run[r], mx);
            float alpha = __expf(m_run[r] - mn);
            m_run[r] = mn;
            float rowsum = 0.f;
#pragma unroll
            for (int nt = 0; nt < 4; nt++) {
                float pv = __expf(sc[nt][r] - mn);
                Ps[w][(lg * 4 + r) * 72 + nt * 16 + la] = f2b(pv);
                rowsum += pv;
            }
#pragma unroll
            for (int sh = 1; sh < 16; sh <<= 1) rowsum += __shfl_xor(rowsum, sh, 64);
            l_run[r] = l_run[r] * alpha + rowsum;
#pragma unroll
            for (int nt = 0; nt < 8; nt++) o_acc[nt][r] *= alpha;
        }
        // ---- PV (Ps is per-wave: no barrier needed; compiler orders via lgkmcnt) ----
        __builtin_amdgcn_s_setprio(1);
#pragma unroll
        for (int kk = 0; kk < 2; kk++) {
            short8 pf = *(const short8*)&Ps[w][la * 72 + kk * 32 + lg * 8];
            int cc = (kk * 32 + lg * 8) ^ swr;
#pragma unroll
            for (int nt = 0; nt < 8; nt++) {
                short8 vf = *(const short8*)&Vt[cur][(nt * 16 + la) * 64 + cc];
                o_acc[nt] = __builtin_amdgcn_mfma_f32_16x16x32_bf16(pf, vf, o_acc[nt], 0, 0, 0);
            }
        }
        __builtin_amdgcn_s_setprio(0);
        __builtin_amdgcn_s_barrier();
        cur ^= 1;
    }
#undef ASTAGE
#pragma unroll
    for (int nt = 0; nt < 8; nt++) {
#pragma unroll
        for (int r = 0; r < 4; r++) {
            int sq = w * 16 + lg * 4 + r;
            po[(((size_t)p * 64 + bh) * 64 + sq) * 128 + nt * 16 + la] = f2b(o_acc[nt][r]);
        }
    }
    if (la == 0) {
#pragma unroll
        for (int r = 0; r < 4; r++) {
            int sq = w * 16 + lg * 4 + r;
            size_t mlb = (((size_t)p * 64 + bh) * 64 + sq) * 2;
            pml[mlb] = m_run[r];
            pml[mlb + 1] = l_run[r];
        }
    }
}

// ---------------- attention reduce: combine NSPLIT partials -> AO bf16 ----------------
__global__ __launch_bounds__(256) void k_attn_red(
    const u16* __restrict__ po, const float* __restrict__ pml, u16* __restrict__ AO) {
    int h = blockIdx.x, b = blockIdx.y;
    int bh = b * NH + h;
    __shared__ float wgt[NSPLIT][64];
    int tid = threadIdx.x;
    if (tid < 64) {
        int q = tid;
        float m[NSPLIT], l[NSPLIT], M = -3e38f;
#pragma unroll
        for (int p = 0; p < NSPLIT; p++) {
            size_t mlb = (((size_t)p * 64 + bh) * 64 + q) * 2;
            m[p] = pml[mlb]; l[p] = pml[mlb + 1];
            M = fmaxf(M, m[p]);
        }
        float L = 0.f;
#pragma unroll
        for (int p = 0; p < NSPLIT; p++) L += l[p] * __expf(m[p] - M);
        float inv = 1.0f / L;
#pragma unroll
        for (int p = 0; p < NSPLIT; p++) wgt[p][q] = __expf(m[p] - M) * inv;
    }
    __syncthreads();
    for (int e = tid; e < 64 * 128; e += 256) {
        int q = e >> 7, d = e & 127;
        float s = 0.f;
#pragma unroll
        for (int p = 0; p < NSPLIT; p++)
            s += b2f(po[(((size_t)p * 64 + bh) * 64 + q) * 128 + d]) * wgt[p][q];
        AO[((size_t)(b * SQA + q)) * 2048 + h * HD + d] = f2b(s);
    }
}

// ---------------- final GEMM: AO[256][2048] @ WoT -> out f32 --------------------------
__global__ __launch_bounds__(256) void k_gemm_out(
    const u16* __restrict__ A, const u16* __restrict__ WoT, float* __restrict__ out) {
    __shared__ __align__(16) u16 smem[2 * 8192];   // per buf: A 4096 + B 4096 u16
    int m0 = blockIdx.x * 64, n0 = blockIdx.y * 64;
    int tid = threadIdx.x;
    int w = tid >> 6, lane = tid & 63;
    int la = lane & 15, lg = lane >> 4;
    int wm = (w & 1) * 32, wn = (w >> 1) * 32;
    f32x4 acc[2][2];
#pragma unroll
    for (int i = 0; i < 2; i++)
#pragma unroll
        for (int j = 0; j < 2; j++) acc[i][j] = (f32x4){0.f, 0.f, 0.f, 0.f};

    int srow = tid >> 3;
    int scsrc = (((tid & 7) * 16) ^ ((srow & 7) << 4)) >> 1;

#define STAGE_OUT(CB, KB) do {                                                        \
        u16* Ab_ = smem + (CB) * 8192;                                                \
        u16* Bb_ = Ab_ + 4096;                                                        \
        _Pragma("unroll")                                                             \
        for (int h = 0; h < 2; h++)                                                   \
            gload16(A + (size_t)(m0 + srow + h * 32) * DMODEL + (KB) + scsrc,         \
                    Ab_ + h * 2048 + w * 512);                                        \
        _Pragma("unroll")                                                             \
        for (int h = 0; h < 2; h++)                                                   \
            gload16(WoT + (size_t)(n0 + srow + h * 32) * DMODEL + (KB) + scsrc,       \
                    Bb_ + h * 2048 + w * 512);                                        \
    } while (0)

    STAGE_OUT(0, 0);
    int cur = 0;
    int swr = (la & 7) << 3;
    for (int kb = 0; kb < DMODEL; kb += 64) {
        if (kb + 64 < DMODEL) {
            STAGE_OUT(cur ^ 1, kb + 64);
            asm volatile("s_waitcnt vmcnt(4)" ::: "memory");
        } else {
            asm volatile("s_waitcnt vmcnt(0)" ::: "memory");
        }
        __builtin_amdgcn_s_barrier();
        asm volatile("" ::: "memory");
        const u16* Ac = smem + cur * 8192;
        const u16* Bc = Ac + 4096;
#pragma unroll
        for (int kk = 0; kk < 2; kk++) {
            short8 af[2], bf[2];
            int cc = (kk * 32 + lg * 8) ^ swr;
#pragma unroll
            for (int mt = 0; mt < 2; mt++) af[mt] = *(const short8*)&Ac[(wm + mt * 16 + la) * 64 + cc];
#pragma unroll
            for (int nt = 0; nt < 2; nt++) bf[nt] = *(const short8*)&Bc[(wn + nt * 16 + la) * 64 + cc];
#pragma unroll
            for (int mt = 0; mt < 2; mt++)
#pragma unroll
                for (int nt = 0; nt < 2; nt++)
                    acc[mt][nt] = __builtin_amdgcn_mfma_f32_16x16x32_bf16(af[mt], bf[nt], acc[mt][nt], 0, 0, 0);
        }
        __builtin_amdgcn_s_barrier();
        cur ^= 1;
    }
#undef STAGE_OUT

#pragma unroll
    for (int mt = 0; mt < 2; mt++) {
#pragma unroll
        for (int r = 0; r < 4; r++) {
            int gm = m0 + wm + mt * 16 + lg * 4 + r;
#pragma unroll
            for (int nt = 0; nt < 2; nt++)
                out[(size_t)gm * DMODEL + n0 + wn + nt * 16 + la] = acc[mt][nt][r];
        }
    }
}

extern "C" void kernel_launch(void* const* d_in, const int* in_sizes, int n_in,
                              void* d_out, int out_size, void* d_ws, size_t ws_size,
                              hipStream_t stream) {
    (void)in_sizes; (void)n_in; (void)out_size;
    const float* mask    = (const float*)d_in[0];
    const int*   pos_vlm = (const int*)d_in[1];
    const int*   pos_act = (const int*)d_in[2];
    const float* h_vlm   = (const float*)d_in[3];
    const float* h_act   = (const float*)d_in[4];
    const float* k_cache = (const float*)d_in[5];
    const float* v_cache = (const float*)d_in[6];
    // d_in[7] = Wq_vlm -- unused (only action-query outputs are returned)
    const float* Wk_vlm  = (const float*)d_in[8];
    const float* Wv_vlm  = (const float*)d_in[9];
    const float* Wq_act  = (const float*)d_in[10];
    const float* Wk_act  = (const float*)d_in[11];
    const float* Wv_act  = (const float*)d_in[12];
    const float* Wo_act  = (const float*)d_in[13];

    const size_t NEED = 65273856;
    if (ws_size < NEED) return;
    char* ws = (char*)d_ws;
    float* cosT  = (float*)(ws + 0);          // 344064
    float* sinT  = (float*)(ws + 344064);     // 344064
    u16* K_all   = (u16*)(ws + 688128);       // 5505024
    u16* VT_all  = (u16*)(ws + 6193152);      // 5505024  [16][128][1344] (d-major)
    u16* Qbuf    = (u16*)(ws + 11698176);     // 1048576
    u16* AO      = (u16*)(ws + 12746752);     // 1048576
    u16* WkvT    = (u16*)(ws + 13795328);     // 2097152
    u16* WvvT    = (u16*)(ws + 15892480);     // 2097152
    u16* WqaT    = (u16*)(ws + 17989632);     // 8388608
    u16* WkaT    = (u16*)(ws + 26378240);     // 2097152
    u16* WvaT    = (u16*)(ws + 28475392);     // 2097152
    u16* WoT     = (u16*)(ws + 30572544);     // 8388608
    u16* po      = (u16*)(ws + 38961152);     // 7340032
    float* pml   = (float*)(ws + 46301184);   // 458752
    u16* maskS   = (u16*)(ws + 46759936);     // 688128
    u16* hv16    = (u16*)(ws + 47448064);     // 16777216
    u16* ha16    = (u16*)(ws + 64225280);     // 1048576  -> end 65273856

    // merged transposes + prep + v_cache transpose: 3072 + 6288 + 128 blocks
    hipLaunchKernelGGL(k_prep, dim3(9488), dim3(256), 0, stream,
                       mask, k_cache, v_cache, h_vlm, h_act,
                       Wk_vlm, WkvT, Wv_vlm, WvvT, Wk_act, WkaT, Wv_act, WvaT,
                       Wq_act, WqaT, Wo_act, WoT,
                       cosT, sinT, maskS, K_all, VT_all, hv16, ha16);
    hipLaunchKernelGGL(k_gemm_qkv, dim3(304), dim3(256), 0, stream,
                       hv16, ha16, WkvT, WvvT, WqaT, WkaT, WvaT,
                       pos_vlm, pos_act, cosT, sinT, Qbuf, K_all, VT_all);
    hipLaunchKernelGGL(k_attn_split, dim3(16, 4, NSPLIT), dim3(256), 0, stream,
                       Qbuf, K_all, VT_all, maskS, po, pml);
    hipLaunchKernelGGL(k_attn_red, dim3(16, 4), dim3(256), 0, stream, po, pml, AO);
    hipLaunchKernelGGL(k_gemm_out, dim3(4, 32), dim3(256), 0, stream, AO, WoT, (float*)d_out);
}

// Round 3
// 232.657 us; speedup vs baseline: 1.0890x; 1.0042x over previous
//
#include <hip/hip_runtime.h>
#include <cmath>

#define NH 16
#define NKV 4
#define HD 128
#define DMODEL 2048
#define BB 4
#define SQV 1024
#define SQA 64
#define SCACHE 256
#define STOT 1344   // SCACHE + SQV + SQA
#define SQTOT 1088  // SQV + SQA
#define NSPLIT 21   // attention K-partitions: one 64-key chunk per block

typedef unsigned short u16;
typedef __attribute__((ext_vector_type(8))) short short8;
typedef __attribute__((ext_vector_type(4))) float f32x4;

__device__ __forceinline__ float b2f(u16 u) {
    union { float f; unsigned int i; } x; x.i = ((unsigned int)u) << 16; return x.f;
}
__device__ __forceinline__ u16 f2b(float f) {
    unsigned int x = __float_as_uint(f);
    x = x + 0x7fffu + ((x >> 16) & 1u);   // RNE
    return (u16)(x >> 16);
}

// async global->LDS, 16B per lane. LDS dest is wave-uniform base + lane*16 (linear).
__device__ __forceinline__ void gload16(const void* g, void* l) {
    __builtin_amdgcn_global_load_lds((const __attribute__((address_space(1))) void*)g,
                                     (__attribute__((address_space(3))) void*)l, 16, 0, 0);
}

// ---------------- transpose body: fp32 [2048][N] tile -> bf16 [N][2048] ---------------
__device__ __forceinline__ void transpose_body(const float* in, u16* out, int N,
                                               int bx, int by) {
    __shared__ __align__(16) u16 t[64 * 66];
    int n0 = bx * 64, k0 = by * 64;
    int tid = threadIdx.x;
    int r = tid >> 3;
    int c8 = (tid & 7) * 8;
#pragma unroll
    for (int h = 0; h < 2; h++) {
        int k = r + h * 32;
        const float* f = in + (size_t)(k0 + k) * N + n0 + c8;
        float4 a = *(const float4*)f, b = *(const float4*)(f + 4);
        u16 vv[8] = {f2b(a.x), f2b(a.y), f2b(a.z), f2b(a.w),
                     f2b(b.x), f2b(b.y), f2b(b.z), f2b(b.w)};
#pragma unroll
        for (int j = 0; j < 8; j++) t[(c8 + j) * 66 + k] = vv[j];
    }
    __syncthreads();
#pragma unroll
    for (int h = 0; h < 2; h++) {
        int n = r + h * 32;
        short8 v;
#pragma unroll
        for (int j = 0; j < 8; j++) ((u16*)&v)[j] = t[n * 66 + c8 + j];
        *(short8*)(out + (size_t)(n0 + n) * 2048 + k0 + c8) = v;
    }
}

// ------------- v_cache transpose: fp32 [key 256][d 128] -> bf16 VT [d][STOT keys] -----
__device__ __forceinline__ void transpose_vc(const float* vc, u16* VT, int idx) {
    __shared__ __align__(16) u16 tv[64 * 66];
    int bkv = idx >> 3, t8 = idx & 7;
    int key0 = (t8 >> 1) * 64, d0 = (t8 & 1) * 64;
    const float* in = vc + ((size_t)bkv * SCACHE + key0) * HD + d0;
    u16* out = VT + ((size_t)bkv * HD + d0) * STOT + key0;
    int tid = threadIdx.x;
    int r = tid >> 3, c8 = (tid & 7) * 8;
#pragma unroll
    for (int h = 0; h < 2; h++) {
        int k = r + h * 32;                     // key row
        const float* f = in + (size_t)k * HD + c8;
        float4 a = *(const float4*)f, b = *(const float4*)(f + 4);
        u16 vv[8] = {f2b(a.x), f2b(a.y), f2b(a.z), f2b(a.w),
                     f2b(b.x), f2b(b.y), f2b(b.z), f2b(b.w)};
#pragma unroll
        for (int j = 0; j < 8; j++) tv[(c8 + j) * 66 + k] = vv[j];
    }
    __syncthreads();
#pragma unroll
    for (int h = 0; h < 2; h++) {
        int d = r + h * 32;                     // d row of VT
        short8 v;
#pragma unroll
        for (int j = 0; j < 8; j++) ((u16*)&v)[j] = tv[d * 66 + c8 + j];
        *(short8*)(out + (size_t)d * STOT + c8) = v;
    }
}

// ---------------- merged prep: weight transposes + tables + mask + caches + cvt -------
__global__ void k_prep(const float* __restrict__ mask,
                       const float* __restrict__ kc, const float* __restrict__ vc,
                       const float* __restrict__ hv, const float* __restrict__ ha,
                       const float* __restrict__ w0, u16* __restrict__ o0,
                       const float* __restrict__ w1, u16* __restrict__ o1,
                       const float* __restrict__ w2, u16* __restrict__ o2,
                       const float* __restrict__ w3, u16* __restrict__ o3,
                       const float* __restrict__ w4, u16* __restrict__ o4,
                       const float* __restrict__ w5, u16* __restrict__ o5,
                       float* __restrict__ cosT, float* __restrict__ sinT,
                       u16* __restrict__ maskS, u16* __restrict__ K_all, u16* __restrict__ VT_all,
                       u16* __restrict__ hv16, u16* __restrict__ ha16) {
    int gx = blockIdx.x, tid = threadIdx.x;
    if (gx < 3072) {
        if (gx < 256)        transpose_body(w0, o0, 512,  gx & 7,  gx >> 3);
        else if (gx < 512)   { int g = gx - 256;  transpose_body(w1, o1, 512,  g & 7,  g >> 3); }
        else if (gx < 768)   { int g = gx - 512;  transpose_body(w2, o2, 512,  g & 7,  g >> 3); }
        else if (gx < 1024)  { int g = gx - 768;  transpose_body(w3, o3, 512,  g & 7,  g >> 3); }
        else if (gx < 2048)  { int g = gx - 1024; transpose_body(w4, o4, 2048, g & 31, g >> 5); }
        else                 { int g = gx - 2048; transpose_body(w5, o5, 2048, g & 31, g >> 5); }
        return;
    }
    int bx = gx - 3072;
    if (bx < 336) {
        int i = bx * 256 + tid;
        if (i < STOT * 64) {
            int p = i >> 6, j = i & 63;
            float inv = __expf(-(float)j * (9.210340371976184f / 64.0f));  // 10000^(-j/64)
            float ang = (float)p * inv;
            cosT[i] = cosf(ang);
            sinT[i] = sinf(ang);
        }
    } else if (bx < 1680) {
        int i = (bx - 336) * 256 + tid;   // 344064 = 1344*256 exact
        int b = i / (SQA * STOT);
        int r = i % (SQA * STOT);
        size_t s = (size_t)b * SQTOT * STOT + (size_t)SQV * STOT + r;
        maskS[i] = f2b(mask[s]);
    } else if (bx < 1936) {
        int i = (bx - 1680) * 256 + tid;  // 65536 groups of 8 (K cache only)
        int e = i * 8;
        int bk = e / (SCACHE * HD);
        int off = e % (SCACHE * HD);
        size_t dst = (size_t)bk * STOT * HD + off;
        const float* fk = kc + e;
        u16 tk[8];
#pragma unroll
        for (int j = 0; j < 8; j++) tk[j] = f2b(fk[j]);
        *(short8*)(K_all + dst) = *(short8*)tk;
    } else if (bx < 6032) {
        int i = (bx - 1936) * 256 + tid;  // 1,048,576 groups of 8
        int e = i * 8;
        const float* f = hv + e;
        float4 a = *(const float4*)f, b = *(const float4*)(f + 4);
        u16 t[8] = {f2b(a.x), f2b(a.y), f2b(a.z), f2b(a.w),
                    f2b(b.x), f2b(b.y), f2b(b.z), f2b(b.w)};
        *(short8*)(hv16 + e) = *(short8*)t;
    } else if (bx < 6288) {
        int i = (bx - 6032) * 256 + tid;  // 65,536 groups of 8
        int e = i * 8;
        const float* f = ha + e;
        float4 a = *(const float4*)f, b = *(const float4*)(f + 4);
        u16 t[8] = {f2b(a.x), f2b(a.y), f2b(a.z), f2b(a.w),
                    f2b(b.x), f2b(b.y), f2b(b.z), f2b(b.w)};
        *(short8*)(ha16 + e) = *(short8*)t;
    } else {
        transpose_vc(vc, VT_all, bx - 6288);   // 128 blocks
    }
}

// ---------------- fused QKV GEMM: 64x128 tiles, 608 blocks, gload_lds dbuf ------------
// 1D grid 608: bid<512 -> vlm K/V proj (A=hv16[4096][2048]): m0=(bid&63)*64, yy=bid>>6,
//   yy<4 -> K head yy, else V head yy-4.  bid>=512 -> act (A=ha16[256][2048]):
//   g=bid-512: m0=(g&3)*64, ny=g>>2: Q(ny<16) / K(16..19) / V(20..23).
// 48 KiB LDS -> 3 blocks/CU resident; 2.375 blocks/CU grid -> balanced makespan.
__global__ __launch_bounds__(256) void k_gemm_qkv(
    const u16* __restrict__ Avlm, const u16* __restrict__ Aact,
    const u16* __restrict__ WkvT, const u16* __restrict__ WvvT,
    const u16* __restrict__ WqaT, const u16* __restrict__ WkaT, const u16* __restrict__ WvaT,
    const int* __restrict__ pos_vlm, const int* __restrict__ pos_act,
    const float* __restrict__ cosT, const float* __restrict__ sinT,
    u16* __restrict__ Qbuf, u16* __restrict__ K_all, u16* __restrict__ VT_all) {
    // per buffer: A 64x64 (4096 u16) + B 128x64 (8192 u16); double-buffered = 48 KiB.
    __shared__ __align__(16) u16 smem[2 * 12288];
    int tid = threadIdx.x;
    int w = tid >> 6, lane = tid & 63;
    int la = lane & 15, lg = lane >> 4;
    int wm = (w & 1) * 32;
    int c2 = w >> 1;
    int ntab[4] = {c2 * 2, c2 * 2 + 1, c2 * 2 + 4, c2 * 2 + 5};

    const u16* A; const u16* Bt; int m0, n0;
    int path;                 // 0 = vlm-K, 1 = vlm-V, 2 = act-Q, 3 = act-K, 4 = act-V
    int head;
    int bid = blockIdx.x;
    if (bid < 512) {
        m0 = (bid & 63) * 64;
        int yy = bid >> 6;
        path = (yy < 4) ? 0 : 1;
        head = yy & 3;
        n0 = head * 128;
        A = Avlm;
        Bt = (path == 0) ? WkvT : WvvT;
    } else {
        int g = bid - 512;
        m0 = (g & 3) * 64;
        int ny = g >> 2;
        A = Aact;
        if (ny < 16)      { path = 2; head = ny;      Bt = WqaT; n0 = ny * 128; }
        else if (ny < 20) { path = 3; head = ny - 16; Bt = WkaT; n0 = (ny - 16) * 128; }
        else              { path = 4; head = ny - 20; Bt = WvaT; n0 = (ny - 20) * 128; }
    }

    f32x4 acc[2][4];
#pragma unroll
    for (int i = 0; i < 2; i++)
#pragma unroll
        for (int j = 0; j < 4; j++) acc[i][j] = (f32x4){0.f, 0.f, 0.f, 0.f};

    // staging: dest flat byte = tid*16 + h*4096 -> row = h*32 + tid>>3 (128B rows)
    int srow = tid >> 3;
    int scsrc = (((tid & 7) * 16) ^ ((srow & 7) << 4)) >> 1;   // swizzled src col (u16)

#define STAGE_QKV(CB, KB) do {                                                        \
        u16* Ab_ = smem + (CB) * 12288;                                               \
        u16* Bb_ = Ab_ + 4096;                                                        \
        _Pragma("unroll")                                                             \
        for (int h = 0; h < 2; h++)                                                   \
            gload16(A + (size_t)(m0 + srow + h * 32) * DMODEL + (KB) + scsrc,         \
                    Ab_ + h * 2048 + tid * 8);                                        \
        _Pragma("unroll")                                                             \
        for (int h = 0; h < 4; h++)                                                   \
            gload16(Bt + (size_t)(n0 + srow + h * 32) * DMODEL + (KB) + scsrc,        \
                    Bb_ + h * 2048 + tid * 8);                                        \
    } while (0)

    STAGE_QKV(0, 0);
    int cur = 0;
    int swr = (la & 7) << 3;     // read-side XOR swizzle (u16 units); row&7 == la&7
    for (int kb = 0; kb < DMODEL; kb += 64) {
        if (kb + 64 < DMODEL) {
            STAGE_QKV(cur ^ 1, kb + 64);
            asm volatile("s_waitcnt vmcnt(6)" ::: "memory");  // current tile landed
        } else {
            asm volatile("s_waitcnt vmcnt(0)" ::: "memory");
        }
        __builtin_amdgcn_s_barrier();
        asm volatile("" ::: "memory");
        const u16* Ac = smem + cur * 12288;
        const u16* Bc = Ac + 4096;
#pragma unroll
        for (int kk = 0; kk < 2; kk++) {
            short8 af[2], bf[4];
            int cc = (kk * 32 + lg * 8) ^ swr;
#pragma unroll
            for (int mt = 0; mt < 2; mt++)
                af[mt] = *(const short8*)&Ac[(wm + mt * 16 + la) * 64 + cc];
#pragma unroll
            for (int nt = 0; nt < 4; nt++)
                bf[nt] = *(const short8*)&Bc[(ntab[nt] * 16 + la) * 64 + cc];
#pragma unroll
            for (int mt = 0; mt < 2; mt++)
#pragma unroll
                for (int nt = 0; nt < 4; nt++)
                    acc[mt][nt] = __builtin_amdgcn_mfma_f32_16x16x32_bf16(af[mt], bf[nt], acc[mt][nt], 0, 0, 0);
        }
        __builtin_amdgcn_s_barrier();
        cur ^= 1;
    }
#undef STAGE_QKV

#pragma unroll
    for (int mt = 0; mt < 2; mt++) {
#pragma unroll
        for (int r = 0; r < 4; r++) {
            int gm = m0 + wm + mt * 16 + lg * 4 + r;
            if (path <= 1) {                       // vlm K/V
                int b = gm >> 10, s = gm & 1023;
                if (path == 0) {
                    size_t base = ((size_t)(b * NKV + head) * STOT + SCACHE + s) * HD;
                    int pos = pos_vlm[gm];
#pragma unroll
                    for (int i = 0; i < 2; i++) {
                        int dlo = ntab[i] * 16 + la;  // in [0,64)
                        float x1 = acc[mt][i][r], x2 = acc[mt][i + 2][r];
                        float cs = cosT[pos * 64 + dlo], sn = sinT[pos * 64 + dlo];
                        K_all[base + dlo]      = f2b(x1 * cs - x2 * sn);
                        K_all[base + dlo + 64] = f2b(x2 * cs + x1 * sn);
                    }
                } else {
                    size_t vt = ((size_t)(b * NKV + head) * HD) * STOT + SCACHE + s;
#pragma unroll
                    for (int i = 0; i < 4; i++) {
                        int d = ntab[i] * 16 + la;    // in [0,128)
                        VT_all[vt + (size_t)d * STOT] = f2b(acc[mt][i][r]);
                    }
                }
            } else {                               // action Q/K/V
                int b = gm >> 6, s = gm & 63;
                if (path == 2) {
                    int pos = pos_act[gm];
                    size_t qb = ((size_t)(b * NH + head) * SQA + s) * HD;
#pragma unroll
                    for (int i = 0; i < 2; i++) {
                        int dlo = ntab[i] * 16 + la;
                        float x1 = acc[mt][i][r], x2 = acc[mt][i + 2][r];
                        float cs = cosT[pos * 64 + dlo], sn = sinT[pos * 64 + dlo];
                        Qbuf[qb + dlo]      = f2b(x1 * cs - x2 * sn);
                        Qbuf[qb + dlo + 64] = f2b(x2 * cs + x1 * sn);
                    }
                } else if (path == 3) {
                    int pos = pos_act[gm];
                    size_t base = ((size_t)(b * NKV + head) * STOT + SCACHE + SQV + s) * HD;
#pragma unroll
                    for (int i = 0; i < 2; i++) {
                        int dlo = ntab[i] * 16 + la;
                        float x1 = acc[mt][i][r], x2 = acc[mt][i + 2][r];
                        float cs = cosT[pos * 64 + dlo], sn = sinT[pos * 64 + dlo];
                        K_all[base + dlo]      = f2b(x1 * cs - x2 * sn);
                        K_all[base + dlo + 64] = f2b(x2 * cs + x1 * sn);
                    }
                } else {
                    size_t vt = ((size_t)(b * NKV + head) * HD) * STOT + SCACHE + SQV + s;
#pragma unroll
                    for (int i = 0; i < 4; i++) {
                        int d = ntab[i] * 16 + la;
                        VT_all[vt + (size_t)d * STOT] = f2b(acc[mt][i][r]);
                    }
                }
            }
        }
    }
}

// ---------------- split-K flash attention: grid (NH, BB, NSPLIT=21) ------------------
// ONE 64-key chunk per block: no online softmax, no in-loop dbuf, ONE barrier total.
// K [64key][128d] and Vt [128d][64key] staged via gload_lds with XOR swizzle.
__global__ __launch_bounds__(256) void k_attn_split(
    const u16* __restrict__ Qbuf, const u16* __restrict__ K_all, const u16* __restrict__ VT_all,
    const u16* __restrict__ maskS, u16* __restrict__ po, float* __restrict__ pml) {
    int h = blockIdx.x, b = blockIdx.y, p = blockIdx.z;
    int bh = b * NH + h;
    int kvh = h >> 2;
    const u16* Kb  = K_all  + (size_t)(b * NKV + kvh) * STOT * HD;   // [key][d]
    const u16* VTb = VT_all + (size_t)(b * NKV + kvh) * HD * STOT;   // [d][key]
    const u16* Qb  = Qbuf + (size_t)bh * SQA * HD;
    int tid = threadIdx.x, w = tid >> 6, lane = tid & 63;
    int la = lane & 15, lg = lane >> 4;
    __shared__ __align__(16) u16 Ks[64 * 128];
    __shared__ __align__(16) u16 Vt[128 * 64];
    __shared__ __align__(16) u16 Ps[4][16 * 72];

    // stage K (256B rows) and Vt (128B rows), linear dest + inverse-swizzled source
    int kr = tid >> 4;
    int ksw = (((tid & 15) * 16) ^ ((kr & 7) << 4)) >> 1;    // u16 units, in [0,128)
    int vr = tid >> 3;
    int vsw = (((tid & 7) * 16) ^ ((vr & 7) << 4)) >> 1;     // u16 units, in [0,64)
#pragma unroll
    for (int hh = 0; hh < 4; hh++)
        gload16(Kb + (size_t)(p * 64 + kr + hh * 16) * HD + ksw, &Ks[hh * 2048 + tid * 8]);
#pragma unroll
    for (int hh = 0; hh < 4; hh++)
        gload16(VTb + (size_t)(vr + hh * 32) * STOT + p * 64 + vsw, &Vt[hh * 2048 + tid * 8]);

    short8 qf[4];
#pragma unroll
    for (int kk = 0; kk < 4; kk++)
        qf[kk] = *(const short8*)(Qb + (size_t)(w * 16 + la) * HD + kk * 32 + lg * 8);
    u16 mreg[4][4];
#pragma unroll
    for (int nt = 0; nt < 4; nt++)
#pragma unroll
        for (int r = 0; r < 4; r++)
            mreg[nt][r] = maskS[((size_t)(b * SQA + w * 16 + lg * 4 + r)) * STOT +
                                p * 64 + nt * 16 + la];

    asm volatile("s_waitcnt vmcnt(0)" ::: "memory");
    __builtin_amdgcn_s_barrier();
    asm volatile("" ::: "memory");

    int swr = (la & 7) << 3;
    const float scl = 0.08838834764831845f;  // 1/sqrt(128)
    // ---- QK^T ----
    f32x4 s_acc[4];
#pragma unroll
    for (int nt = 0; nt < 4; nt++) s_acc[nt] = (f32x4){0.f, 0.f, 0.f, 0.f};
    __builtin_amdgcn_s_setprio(1);
#pragma unroll
    for (int kk = 0; kk < 4; kk++) {
        int cc = (kk * 32 + lg * 8) ^ swr;
#pragma unroll
        for (int nt = 0; nt < 4; nt++) {
            short8 kf = *(const short8*)&Ks[(nt * 16 + la) * 128 + cc];
            s_acc[nt] = __builtin_amdgcn_mfma_f32_16x16x32_bf16(qf[kk], kf, s_acc[nt], 0, 0, 0);
        }
    }
    __builtin_amdgcn_s_setprio(0);
    // ---- scores: scale, softclamp, mask ----
    float sc[4][4];
#pragma unroll
    for (int nt = 0; nt < 4; nt++) {
#pragma unroll
        for (int r = 0; r < 4; r++) {
            float sv = s_acc[nt][r] * scl;
            float x = sv * 0.02f;
            float t = __expf(-2.0f * fabsf(x));
            float th = __fdividef(1.0f - t, 1.0f + t);
            sv = copysignf(th, x) * 50.0f;
            sv += b2f(mreg[nt][r]);
            sc[nt][r] = sv;
        }
    }
    // ---- plain (single-chunk) softmax ----
    float m_fin[4], l_fin[4];
#pragma unroll
    for (int r = 0; r < 4; r++) {
        float mx = fmaxf(fmaxf(sc[0][r], sc[1][r]), fmaxf(sc[2][r], sc[3][r]));
#pragma unroll
        for (int sh = 1; sh < 16; sh <<= 1) mx = fmaxf(mx, __shfl_xor(mx, sh, 64));
        float rowsum = 0.f;
#pragma unroll
        for (int nt = 0; nt < 4; nt++) {
            float pv = __expf(sc[nt][r] - mx);
            Ps[w][(lg * 4 + r) * 72 + nt * 16 + la] = f2b(pv);
            rowsum += pv;
        }
#pragma unroll
        for (int sh = 1; sh < 16; sh <<= 1) rowsum += __shfl_xor(rowsum, sh, 64);
        m_fin[r] = mx;
        l_fin[r] = rowsum;
    }
    // ---- PV (Ps per-wave: no barrier; compiler orders via lgkmcnt) ----
    f32x4 o_acc[8];
#pragma unroll
    for (int nt = 0; nt < 8; nt++) o_acc[nt] = (f32x4){0.f, 0.f, 0.f, 0.f};
    __builtin_amdgcn_s_setprio(1);
#pragma unroll
    for (int kk = 0; kk < 2; kk++) {
        short8 pf = *(const short8*)&Ps[w][la * 72 + kk * 32 + lg * 8];
        int cc = (kk * 32 + lg * 8) ^ swr;
#pragma unroll
        for (int nt = 0; nt < 8; nt++) {
            short8 vf = *(const short8*)&Vt[(nt * 16 + la) * 64 + cc];
            o_acc[nt] = __builtin_amdgcn_mfma_f32_16x16x32_bf16(pf, vf, o_acc[nt], 0, 0, 0);
        }
    }
    __builtin_amdgcn_s_setprio(0);
#pragma unroll
    for (int nt = 0; nt < 8; nt++) {
#pragma unroll
        for (int r = 0; r < 4; r++) {
            int sq = w * 16 + lg * 4 + r;
            po[(((size_t)p * 64 + bh) * 64 + sq) * 128 + nt * 16 + la] = f2b(o_acc[nt][r]);
        }
    }
    if (la == 0) {
#pragma unroll
        for (int r = 0; r < 4; r++) {
            int sq = w * 16 + lg * 4 + r;
            size_t mlb = (((size_t)p * 64 + bh) * 64 + sq) * 2;
            pml[mlb] = m_fin[r];
            pml[mlb + 1] = l_fin[r];
        }
    }
}

// ---------------- attention reduce: combine NSPLIT partials -> AO bf16 ----------------
// grid (NH, BB, 4): each block owns 16 q-rows -> 256 blocks, 1/CU.
__global__ __launch_bounds__(256) void k_attn_red(
    const u16* __restrict__ po, const float* __restrict__ pml, u16* __restrict__ AO) {
    int h = blockIdx.x, b = blockIdx.y, qz = blockIdx.z * 16;
    int bh = b * NH + h;
    __shared__ float wgt[NSPLIT][16];
    int tid = threadIdx.x;
    if (tid < 16) {
        int q = qz + tid;
        float m[NSPLIT], l[NSPLIT], M = -3e38f;
#pragma unroll
        for (int p = 0; p < NSPLIT; p++) {
            size_t mlb = (((size_t)p * 64 + bh) * 64 + q) * 2;
            m[p] = pml[mlb]; l[p] = pml[mlb + 1];
            M = fmaxf(M, m[p]);
        }
        float L = 0.f;
#pragma unroll
        for (int p = 0; p < NSPLIT; p++) L += l[p] * __expf(m[p] - M);
        float inv = 1.0f / L;
#pragma unroll
        for (int p = 0; p < NSPLIT; p++) wgt[p][tid] = __expf(m[p] - M) * inv;
    }
    __syncthreads();
    for (int e = tid; e < 16 * 128; e += 256) {
        int q = qz + (e >> 7), d = e & 127;
        float s = 0.f;
#pragma unroll
        for (int p = 0; p < NSPLIT; p++)
            s += b2f(po[(((size_t)p * 64 + bh) * 64 + q) * 128 + d]) * wgt[p][e >> 7];
        AO[((size_t)(b * SQA + q)) * 2048 + h * HD + d] = f2b(s);
    }
}

// ---------------- final GEMM: AO[256][2048] @ WoT -> out f32, 32x64 tiles -------------
// grid (8, 32) = 256 blocks (1/CU; was 128 = half the GPU idle). 24 KiB LDS.
__global__ __launch_bounds__(256) void k_gemm_out(
    const u16* __restrict__ A, const u16* __restrict__ WoT, float* __restrict__ out) {
    __shared__ __align__(16) u16 smem[2 * 6144];   // per buf: A 32x64 (2048) + B 64x64 (4096)
    int m0 = blockIdx.x * 32, n0 = blockIdx.y * 64;
    int tid = threadIdx.x;
    int w = tid >> 6, lane = tid & 63;
    int la = lane & 15, lg = lane >> 4;
    int wm = (w & 1) * 16, wn = (w >> 1) * 32;
    f32x4 acc[2];
#pragma unroll
    for (int j = 0; j < 2; j++) acc[j] = (f32x4){0.f, 0.f, 0.f, 0.f};

    int srow = tid >> 3;
    int scsrc = (((tid & 7) * 16) ^ ((srow & 7) << 4)) >> 1;

#define STAGE_OUT(CB, KB) do {                                                        \
        u16* Ab_ = smem + (CB) * 6144;                                                \
        u16* Bb_ = Ab_ + 2048;                                                        \
        gload16(A + (size_t)(m0 + srow) * DMODEL + (KB) + scsrc, Ab_ + tid * 8);      \
        _Pragma("unroll")                                                             \
        for (int h = 0; h < 2; h++)                                                   \
            gload16(WoT + (size_t)(n0 + srow + h * 32) * DMODEL + (KB) + scsrc,       \
                    Bb_ + h * 2048 + tid * 8);                                        \
    } while (0)

    STAGE_OUT(0, 0);
    int cur = 0;
    int swr = (la & 7) << 3;
    for (int kb = 0; kb < DMODEL; kb += 64) {
        if (kb + 64 < DMODEL) {
            STAGE_OUT(cur ^ 1, kb + 64);
            asm volatile("s_waitcnt vmcnt(3)" ::: "memory");
        } else {
            asm volatile("s_waitcnt vmcnt(0)" ::: "memory");
        }
        __builtin_amdgcn_s_barrier();
        asm volatile("" ::: "memory");
        const u16* Ac = smem + cur * 6144;
        const u16* Bc = Ac + 2048;
#pragma unroll
        for (int kk = 0; kk < 2; kk++) {
            int cc = (kk * 32 + lg * 8) ^ swr;
            short8 af = *(const short8*)&Ac[(wm + la) * 64 + cc];
            short8 bf[2];
#pragma unroll
            for (int nt = 0; nt < 2; nt++) bf[nt] = *(const short8*)&Bc[(wn + nt * 16 + la) * 64 + cc];
#pragma unroll
            for (int nt = 0; nt < 2; nt++)
                acc[nt] = __builtin_amdgcn_mfma_f32_16x16x32_bf16(af, bf[nt], acc[nt], 0, 0, 0);
        }
        __builtin_amdgcn_s_barrier();
        cur ^= 1;
    }
#undef STAGE_OUT

#pragma unroll
    for (int r = 0; r < 4; r++) {
        int gm = m0 + wm + lg * 4 + r;
#pragma unroll
        for (int nt = 0; nt < 2; nt++)
            out[(size_t)gm * DMODEL + n0 + wn + nt * 16 + la] = acc[nt][r];
    }
}

extern "C" void kernel_launch(void* const* d_in, const int* in_sizes, int n_in,
                              void* d_out, int out_size, void* d_ws, size_t ws_size,
                              hipStream_t stream) {
    (void)in_sizes; (void)n_in; (void)out_size;
    const float* mask    = (const float*)d_in[0];
    const int*   pos_vlm = (const int*)d_in[1];
    const int*   pos_act = (const int*)d_in[2];
    const float* h_vlm   = (const float*)d_in[3];
    const float* h_act   = (const float*)d_in[4];
    const float* k_cache = (const float*)d_in[5];
    const float* v_cache = (const float*)d_in[6];
    // d_in[7] = Wq_vlm -- unused (only action-query outputs are returned)
    const float* Wk_vlm  = (const float*)d_in[8];
    const float* Wv_vlm  = (const float*)d_in[9];
    const float* Wq_act  = (const float*)d_in[10];
    const float* Wk_act  = (const float*)d_in[11];
    const float* Wv_act  = (const float*)d_in[12];
    const float* Wo_act  = (const float*)d_in[13];

    const size_t NEED = 80183296;
    if (ws_size < NEED) return;
    char* ws = (char*)d_ws;
    float* cosT  = (float*)(ws + 0);          // 344064
    float* sinT  = (float*)(ws + 344064);     // 344064
    u16* K_all   = (u16*)(ws + 688128);       // 5505024
    u16* VT_all  = (u16*)(ws + 6193152);      // 5505024  [16][128][1344] (d-major)
    u16* Qbuf    = (u16*)(ws + 11698176);     // 1048576
    u16* AO      = (u16*)(ws + 12746752);     // 1048576
    u16* WkvT    = (u16*)(ws + 13795328);     // 2097152
    u16* WvvT    = (u16*)(ws + 15892480);     // 2097152
    u16* WqaT    = (u16*)(ws + 17989632);     // 8388608
    u16* WkaT    = (u16*)(ws + 26378240);     // 2097152
    u16* WvaT    = (u16*)(ws + 28475392);     // 2097152
    u16* WoT     = (u16*)(ws + 30572544);     // 8388608
    u16* po      = (u16*)(ws + 38961152);     // 22020096 (21 splits)
    float* pml   = (float*)(ws + 60981248);   // 688128
    u16* maskS   = (u16*)(ws + 61669376);     // 688128
    u16* hv16    = (u16*)(ws + 62357504);     // 16777216
    u16* ha16    = (u16*)(ws + 79134720);     // 1048576  -> end 80183296

    // merged transposes + prep + v_cache transpose: 3072 + 6288 + 128 blocks
    hipLaunchKernelGGL(k_prep, dim3(9488), dim3(256), 0, stream,
                       mask, k_cache, v_cache, h_vlm, h_act,
                       Wk_vlm, WkvT, Wv_vlm, WvvT, Wk_act, WkaT, Wv_act, WvaT,
                       Wq_act, WqaT, Wo_act, WoT,
                       cosT, sinT, maskS, K_all, VT_all, hv16, ha16);
    hipLaunchKernelGGL(k_gemm_qkv, dim3(608), dim3(256), 0, stream,
                       hv16, ha16, WkvT, WvvT, WqaT, WkaT, WvaT,
                       pos_vlm, pos_act, cosT, sinT, Qbuf, K_all, VT_all);
    hipLaunchKernelGGL(k_attn_split, dim3(16, 4, NSPLIT), dim3(256), 0, stream,
                       Qbuf, K_all, VT_all, maskS, po, pml);
    hipLaunchKernelGGL(k_attn_red, dim3(16, 4, 4), dim3(256), 0, stream, po, pml, AO);
    hipLaunchKernelGGL(k_gemm_out, dim3(8, 32), dim3(256), 0, stream, AO, WoT, (float*)d_out);
}